// Round 3
// baseline (293.775 us; speedup 1.0000x reference)
//
#include <hip/hip_runtime.h>
#include <math.h>

// ---------------------------------------------------------------------------
// MultiChannelAttention on MI355X (gfx950)
// out = softmax(causal(rope(xWq^T) rope(xWk^T)^T / sqrt(C))) (xWv^T) Wf^T + b
// B=4 T=2048 C=1024. bf16 MFMA (16x16x32), fp32 accum.
// R11: core4 -- true software pipeline. BK=32, 4 LDS buffers (96 KiB),
//      prefetch 3 K-tiles (9 loads in flight, vmcnt(6)/K-tile), and
//      REGISTER-double-buffered fragments: tile kt+1's ds_reads issue right
//      after the certification barrier and drain UNDER tile kt's 16 MFMA.
//      2 barriers/K-tile, no sched_barrier pins, no explicit lgkmcnt
//      (compiler emits partial waits). V grid gets bijective XCD remap.
// R10 (regressed, reverted): lockstep 2-phase + sched_barrier(0) pins.
// R9: 128x256-tile 512-thread 8-wave core, counted vmcnt + setprio.
// R8: V projection computes Vt natively (A=Wv, B=x). R7: triangular score
//     grid; pv longest-K-first. R5: native v_sin/v_cos RoPE. R2: fused
//     exp-softmax (P=exp(s) bf16 + atomic row sums).
// Workspace layout (121 MB):
//   [0,16) xb  [16,24) Wq/Wk/Wv/Wf bf16  [24,40) Q  [40,56) K
//   [56,72) Vt  [72,88) O  [88,120) P bf16  [120,+32K) row_sum
// ---------------------------------------------------------------------------

#define AS1(p) ((__attribute__((address_space(1))) void*)(p))
#define AS3(p) ((__attribute__((address_space(3))) void*)(p))

typedef __attribute__((ext_vector_type(8))) short bf16x8;
typedef __attribute__((ext_vector_type(4))) float f32x4;

__device__ __forceinline__ unsigned short f2bf(float f) {
  unsigned int u = __float_as_uint(f);
  u += 0x7fffu + ((u >> 16) & 1u);   // round-to-nearest-even
  return (unsigned short)(u >> 16);
}

// ---- fp32 -> bf16 cast for x + 4 weight matrices, one launch --------------
__global__ __launch_bounds__(256) void cast_all(
    const float* __restrict__ x, const float* __restrict__ Wq,
    const float* __restrict__ Wk, const float* __restrict__ Wv,
    const float* __restrict__ Wf,
    unsigned short* __restrict__ xb, unsigned short* __restrict__ Wqb,
    unsigned short* __restrict__ Wkb, unsigned short* __restrict__ Wvb,
    unsigned short* __restrict__ Wfb) {
  int i = blockIdx.x * 256 + threadIdx.x;           // float4 index
  const float* src; unsigned short* dst; int off;
  if (i < 2097152) { src = x; dst = xb; off = i; }
  else {
    int j = i - 2097152;
    int w = j >> 18; off = j & 262143;              // 262144 float4 per W
    src = (w == 0) ? Wq : (w == 1) ? Wk : (w == 2) ? Wv : Wf;
    dst = (w == 0) ? Wqb : (w == 1) ? Wkb : (w == 2) ? Wvb : Wfb;
  }
  float4 f = ((const float4*)src)[off];
  ushort4 o;
  o.x = f2bf(f.x); o.y = f2bf(f.y); o.z = f2bf(f.z); o.w = f2bf(f.w);
  ((ushort4*)dst)[off] = o;
}

// ---- legacy 128x128 bt-GEMM core (256 thr), used by score_exp / pv_gemm ---
__device__ __forceinline__ void gemm_core(const unsigned short* __restrict__ At, long long lda,
                                          const unsigned short* __restrict__ Bt, long long ldb,
                                          int K, f32x4 (&acc)[4][4],
                                          unsigned short* As, unsigned short* Bs) {
  const int tid  = threadIdx.x;
  const int lane = tid & 63;
  const int w    = tid >> 6;
  const int wm   = (w & 1) << 6;
  const int wn   = (w >> 1) << 6;
  const int fr   = lane & 15;
  const int fq   = lane >> 4;
  const int srow = tid >> 2;
  const int scol = (tid & 3) << 3;
  const int lg   = ((tid & 3) ^ ((srow >> 1) & 3)) << 3;
  const unsigned short* a0 = At + (long long)srow * lda + lg;
  const unsigned short* a1 = At + (long long)(srow + 64) * lda + lg;
  const unsigned short* b0 = Bt + (long long)srow * ldb + lg;
  const unsigned short* b1 = Bt + (long long)(srow + 64) * ldb + lg;
  unsigned short* As0 = As + srow * 32 + scol;
  unsigned short* As1 = As + (srow + 64) * 32 + scol;
  unsigned short* Bs0 = Bs + srow * 32 + scol;
  unsigned short* Bs1 = Bs + (srow + 64) * 32 + scol;
  const int pg = (fq ^ ((fr >> 1) & 3)) << 3;
  for (int k0 = 0; k0 < K; k0 += 32) {
    __builtin_amdgcn_global_load_lds(AS1(a0 + k0), AS3(As0), 16, 0, 0);
    __builtin_amdgcn_global_load_lds(AS1(a1 + k0), AS3(As1), 16, 0, 0);
    __builtin_amdgcn_global_load_lds(AS1(b0 + k0), AS3(Bs0), 16, 0, 0);
    __builtin_amdgcn_global_load_lds(AS1(b1 + k0), AS3(Bs1), 16, 0, 0);
    __syncthreads();
    bf16x8 af[4], bfr[4];
#pragma unroll
    for (int i = 0; i < 4; i++)
      af[i] = *(const bf16x8*)(As + (wm + i * 16 + fr) * 32 + pg);
#pragma unroll
    for (int i = 0; i < 4; i++)
      bfr[i] = *(const bf16x8*)(Bs + (wn + i * 16 + fr) * 32 + pg);
#pragma unroll
    for (int mi = 0; mi < 4; mi++)
#pragma unroll
      for (int ni = 0; ni < 4; ni++)
        acc[mi][ni] = __builtin_amdgcn_mfma_f32_16x16x32_bf16(af[mi], bfr[ni], acc[mi][ni], 0, 0, 0);
    __syncthreads();
  }
}

// ---- LDS repack + coalesced bf16x8 store of one mi-slice (legacy) ---------
__device__ __forceinline__ void repack_store_mi(unsigned short (&vals)[4][4],
                                                unsigned short* sh, int mi,
                                                int m0, int n0, long long ldo,
                                                unsigned short* __restrict__ Out) {
  const int tid = threadIdx.x, lane = tid & 63, w = tid >> 6;
  const int half = w & 1, wn = (w >> 1) << 6;
  const int cl = lane & 15, q4 = lane >> 4;
  const int lr = half * 16 + q4 * 4;
#pragma unroll
  for (int ni = 0; ni < 4; ni++)
#pragma unroll
    for (int rr = 0; rr < 4; rr++)
      sh[(lr + rr) * 132 + wn + ni * 16 + cl] = vals[ni][rr];
  __syncthreads();
#pragma unroll
  for (int it = 0; it < 2; ++it) {
    int row = (tid >> 4) + it * 16;          // 0..31
    int c8 = (tid & 15) << 3;                // 0..120
    bf16x8 v = *(const bf16x8*)(sh + row * 132 + c8);
    int gr = m0 + (row < 16 ? mi * 16 + row : 48 + mi * 16 + row);
    *(bf16x8*)(Out + (long long)gr * ldo + n0 + c8) = v;
  }
  __syncthreads();
}

// ---------------------------------------------------------------------------
// core4: 128x256-tile GEMM, 512 thr = 8 waves (2M x 4N), per-wave 64x64 out
// (acc[4][4]). BK=32; 4 LDS buffers of 24 KiB: [A 128x32 | B 256x32] each,
// 16B chunks swizzled c ^= (row>>1)&3 (pre-swizzled GLOBAL source, linear
// LDS dest; same XOR on ds_read). Pipeline:
//   - 3 K-tiles of global prefetch in flight (9 loads/wave, vmcnt(6) gate)
//   - fragments register-double-buffered: reads of tile kt+1 issue after the
//     certification barrier and drain under tile kt's 16 MFMA.
// Per K-tile: 1 stage (3 loads), 1 vmcnt gate, 2 barriers, 8 ds_read_b128,
// 16 MFMA. No sched_barrier, no explicit lgkmcnt (compiler partial waits).
// C[m,n] = sum_k A[m,k]*B[n,k], A/B bf16 K-fast. nkt = K/32 (even, >=4).
// ---------------------------------------------------------------------------
__device__ __forceinline__ void core4(
    const unsigned short* __restrict__ A, long long lda,
    const unsigned short* __restrict__ B, long long ldb,
    int nkt, f32x4 (&acc)[4][4], unsigned short* lds) {
  const int tid  = threadIdx.x;
  const int lane = tid & 63;
  const int w    = tid >> 6;
  const int wr   = w >> 2;            // 0..1
  const int wc   = w & 3;             // 0..3
  const int fr   = lane & 15;
  const int fq   = lane >> 4;
  const int csel = (fq ^ ((fr >> 1) & 3)) << 3;   // fragment chunk swizzle
  const int srow = tid >> 2;                      // staging row 0..127
  const int scsw = ((tid & 3) ^ ((srow >> 1) & 3)) << 3;
  const unsigned short* Asrc  = A + (long long)srow * lda + scsw;
  const unsigned short* Bsrc0 = B + (long long)srow * ldb + scsw;
  const unsigned short* Bsrc1 = B + (long long)(srow + 128) * ldb + scsw;
  unsigned short* dsta = lds + tid * 8;           // per-thread 16B slot

  auto stage = [&](int kt) {
    const int bo = (kt & 3) * 12288;
    const long long ko = (long long)kt * 32;
    __builtin_amdgcn_global_load_lds(AS1(Asrc + ko),  AS3(dsta + bo),        16, 0, 0);
    __builtin_amdgcn_global_load_lds(AS1(Bsrc0 + ko), AS3(dsta + bo + 4096), 16, 0, 0);
    __builtin_amdgcn_global_load_lds(AS1(Bsrc1 + ko), AS3(dsta + bo + 8192), 16, 0, 0);
  };
  auto rdfrag = [&](int kt, bf16x8 (&r)[8]) {
    const unsigned short* Ab = lds + (kt & 3) * 12288 + (wr * 64 + fr) * 32 + csel;
    const unsigned short* Bb = lds + (kt & 3) * 12288 + 4096 + (wc * 64 + fr) * 32 + csel;
#pragma unroll
    for (int mi = 0; mi < 4; ++mi) r[mi] = *(const bf16x8*)(Ab + mi * 512);
#pragma unroll
    for (int nj = 0; nj < 4; ++nj) r[4 + nj] = *(const bf16x8*)(Bb + nj * 512);
  };

  bf16x8 ra[8], rb[8];
  // prologue: 3 tiles in flight; certify tile0; preload its fragments
  stage(0); stage(1); stage(2);
  asm volatile("s_waitcnt vmcnt(6)" ::: "memory");
  __builtin_amdgcn_s_barrier();
  rdfrag(0, ra);

  auto body = [&](int kt, bf16x8 (&cur)[8], bf16x8 (&nxt)[8]) {
    // stage kt+3 (overwrites buf[kt-1], whose reads were consumed by kt-1's
    // MFMA before kt-1's trailing barrier); gate certifies tile kt+1.
    if (kt + 3 < nkt) {
      stage(kt + 3);
      asm volatile("s_waitcnt vmcnt(6)" ::: "memory");
    } else if (kt + 2 < nkt) {
      asm volatile("s_waitcnt vmcnt(3)" ::: "memory");
    } else if (kt + 1 < nkt) {
      asm volatile("s_waitcnt vmcnt(0)" ::: "memory");
    }
    if (kt + 1 < nkt) {
      __builtin_amdgcn_s_barrier();       // tile kt+1 visible to all waves
      rdfrag(kt + 1, nxt);                // drains under the MFMA below
    }
    __builtin_amdgcn_s_setprio(1);
#pragma unroll
    for (int mi = 0; mi < 4; ++mi)
#pragma unroll
      for (int nj = 0; nj < 4; ++nj)
        acc[mi][nj] = __builtin_amdgcn_mfma_f32_16x16x32_bf16(cur[mi], cur[4 + nj], acc[mi][nj], 0, 0, 0);
    __builtin_amdgcn_s_setprio(0);
    if (kt + 1 < nkt) __builtin_amdgcn_s_barrier();  // WAR guard for next stage
  };

#pragma unroll 1
  for (int kt = 0; kt < nkt; kt += 2) {   // reg ping-pong, nkt even
    body(kt, ra, rb);
    body(kt + 1, rb, ra);
  }
}

// ---- Q/K/V projections; Q/K get RoPE; V computed AS Vt (swapped operands) -
// Grid (64, 4, 3), 512 threads. Q/K: x=m-tile(128), y=n-tile(256) -- the
// natural dispatch is already XCD-grouped (gridDim.x=64 ≡ 0 mod 8).
// V: bijective XCD remap so each XCD's 32 co-resident blocks touch
// whole Wv (2 MB) + 4 x s-panels (2 MB) = L2-resident working set.
__global__ __launch_bounds__(512, 2) void proj_rope(
    const unsigned short* __restrict__ xb,
    const unsigned short* __restrict__ Wq, const unsigned short* __restrict__ Wk,
    const unsigned short* __restrict__ Wv,
    const float* __restrict__ bq, const float* __restrict__ bk, const float* __restrict__ bv,
    unsigned short* __restrict__ Q, unsigned short* __restrict__ Ko,
    unsigned short* __restrict__ Vt) {
  __shared__ unsigned short lds[49152];   // 96 KiB: GEMM 4-buf, then repack
  const int which = blockIdx.z;
  const int tid = threadIdx.x, lane = tid & 63, w = tid >> 6;
  const int wr = w >> 2, wc = w & 3;
  const int cl = lane & 15, q4 = lane >> 4;

  f32x4 acc[4][4];
#pragma unroll
  for (int i = 0; i < 4; i++)
#pragma unroll
    for (int j = 0; j < 4; j++)
#pragma unroll
      for (int k = 0; k < 4; k++) acc[i][j][k] = 0.0f;

  if (which == 2) {
    // ---- V path: Vt[d,s] = sum_k Wv[d,k] x[s,k]; A = Wv (m=d), B = x (n=s)
    const int p = blockIdx.x + 64 * blockIdx.y;     // physical 0..255
    const int m0 = ((p >> 3) & 7) * 128;            // d tile
    const int n0 = (4 * (p & 7) + (p >> 6)) * 256;  // global s tile (XCD remap)
    core4(Wv + (long long)m0 * 1024, 1024, xb + (long long)n0 * 1024, 1024, 32, acc, lds);
    __syncthreads();
    const int b = n0 >> 11, sloc = n0 & 2047;
#pragma unroll
    for (int mi = 0; mi < 4; ++mi) {
      const int lr = wr * 64 + mi * 16 + q4 * 4;
#pragma unroll
      for (int rr = 0; rr < 4; ++rr) {
        const float b_ = bv[m0 + lr + rr];          // bias per d-row
#pragma unroll
        for (int nj = 0; nj < 4; ++nj)
          lds[(lr + rr) * 264 + wc * 64 + nj * 16 + cl] = f2bf(acc[mi][nj][rr] + b_);
      }
    }
    __syncthreads();
    unsigned short* Outb = Vt + (long long)b * 1024 * 2048;
#pragma unroll
    for (int it = 0; it < 8; ++it) {
      int c = it * 512 + tid;
      int row = c >> 5, c8 = (c & 31) << 3;
      bf16x8 v = *(const bf16x8*)(lds + row * 264 + c8);
      *(bf16x8*)(Outb + (long long)(m0 + row) * 2048 + sloc + c8) = v;
    }
    return;
  }

  // ---- Q/K path: bias + RoPE (native sin/cos) ----
  const int m0 = blockIdx.x * 128;    // token rows
  const int n0 = blockIdx.y * 256;    // feature cols
  const unsigned short* W = which == 0 ? Wq : Wk;
  const float* bias = which == 0 ? bq : bk;
  unsigned short* Out = which == 0 ? Q : Ko;

  core4(xb + (long long)m0 * 1024, 1024, W + (long long)n0 * 1024, 1024, 32, acc, lds);
  __syncthreads();

  const float NEG_L2T_512 = -0.025952563239354392f;  // -log2(10000)/512
  const float INV2PI = 0.15915494309189535f;
  float freqn[4];
#pragma unroll
  for (int nj = 0; nj < 4; ++nj) {
    int gn = n0 + wc * 64 + nj * 16 + cl;
    freqn[nj] = exp2f(NEG_L2T_512 * (float)(gn >> 1));
  }
#pragma unroll
  for (int mi = 0; mi < 4; ++mi) {
    const int lr = wr * 64 + mi * 16 + q4 * 4;
    const int t0 = (m0 & 2047) + lr;   // batch-local time (tiles never straddle)
#pragma unroll
    for (int nj = 0; nj < 4; ++nj) {
      const int gn = n0 + wc * 64 + nj * 16 + cl;
      const float bi = bias[gn];
#pragma unroll
      for (int rr = 0; rr < 4; ++rr) {
        float v = acc[mi][nj][rr] + bi;
        float partner = __shfl_xor(v, 1, 64);
        float ang = (float)(t0 + rr) * freqn[nj];
        float rev = ang * INV2PI;
        rev = rev - floorf(rev);           // v_sin/v_cos domain
        float c_ = __builtin_amdgcn_cosf(rev);
        float s_ = __builtin_amdgcn_sinf(rev);
        v = v * c_ + ((gn & 1) ? partner : -partner) * s_;
        lds[(lr + rr) * 264 + wc * 64 + nj * 16 + cl] = f2bf(v);
      }
    }
  }
  __syncthreads();
#pragma unroll
  for (int it = 0; it < 8; ++it) {
    int c = it * 512 + tid;
    int row = c >> 5, c8 = (c & 31) << 3;
    bf16x8 v = *(const bf16x8*)(lds + row * 264 + c8);
    *(bf16x8*)(Out + (long long)(m0 + row) * 1024 + n0 + c8) = v;
  }
}

// ---- P = exp(Q K^T / sqrt(C)) (causal-zeroed), bf16; row sums via atomics -
__global__ __launch_bounds__(256) void score_exp(const unsigned short* __restrict__ Q,
                                                 const unsigned short* __restrict__ Kk,
                                                 unsigned short* __restrict__ P,
                                                 float* __restrict__ row_sum) {
  __shared__ unsigned short sh[8192];
  const int bx = blockIdx.x;
  int i = (int)((sqrtf(8.0f * (float)bx + 1.0f) - 1.0f) * 0.5f);
  while ((i + 1) * (i + 2) / 2 <= bx) ++i;
  while (i * (i + 1) / 2 > bx) --i;
  const int j = bx - i * (i + 1) / 2;       // 0..i
  const int b = blockIdx.z;
  const int m0 = i * 128, n0 = j * 128;
  const unsigned short* Qb = Q + (long long)b * 2048 * 1024;
  const unsigned short* Kb = Kk + (long long)b * 2048 * 1024;
  unsigned short* Pb = P + (long long)b * 2048 * 2048;
  float* rs = row_sum + b * 2048;

  f32x4 acc[4][4];
#pragma unroll
  for (int ii = 0; ii < 4; ii++)
#pragma unroll
    for (int jj = 0; jj < 4; jj++)
#pragma unroll
      for (int k = 0; k < 4; k++) acc[ii][jj][k] = 0.0f;

  gemm_core(Qb + (long long)m0 * 1024, 1024, Kb + (long long)n0 * 1024, 1024, 1024, acc, sh, sh + 4096);

  const int tid = threadIdx.x, lane = tid & 63, w = tid >> 6;
  const int wm = (w & 1) << 6, wn = (w >> 1) << 6;
  const int cl = lane & 15, q4 = lane >> 4;
  const bool diag = (i == j);
#pragma unroll
  for (int mi = 0; mi < 4; mi++) {
    unsigned short vals[4][4];
    float rsum[4] = {0.f, 0.f, 0.f, 0.f};
#pragma unroll
    for (int ni = 0; ni < 4; ni++) {
      const int gn = n0 + wn + ni * 16 + cl;
#pragma unroll
      for (int rr = 0; rr < 4; rr++) {
        const int gm = m0 + wm + mi * 16 + q4 * 4 + rr;
        float e = (diag && gn > gm) ? 0.0f : __expf(acc[mi][ni][rr] * 0.03125f);
        vals[ni][rr] = f2bf(e);
        rsum[rr] += e;
      }
    }
#pragma unroll
    for (int rr = 0; rr < 4; rr++) {
#pragma unroll
      for (int off = 1; off < 16; off <<= 1) rsum[rr] += __shfl_xor(rsum[rr], off, 64);
    }
    if (cl == 0) {
      const int gm = m0 + wm + mi * 16 + q4 * 4;
#pragma unroll
      for (int rr = 0; rr < 4; rr++) atomicAdd(&rs[gm + rr], rsum[rr]);
    }
    repack_store_mi(vals, sh, mi, m0, n0, 2048, Pb);
  }
}

// ---- O = (P V) / row_sum; longest-K blocks dispatched first ---------------
__global__ __launch_bounds__(256) void pv_gemm(const unsigned short* __restrict__ P,
                                               const unsigned short* __restrict__ Vt,
                                               const float* __restrict__ row_sum,
                                               unsigned short* __restrict__ O) {
  __shared__ unsigned short sh[8192];
  const int b = blockIdx.z;
  const int mt = 15 - blockIdx.x;   // longest K first (tail balance)
  const int m0 = mt * 128;          // t tile
  const int n0 = blockIdx.y * 128;  // d tile
  const unsigned short* Pb = P + (long long)b * 2048 * 2048;
  const unsigned short* Vb = Vt + (long long)b * 1024 * 2048;
  const float* rs = row_sum + b * 2048;
  const int K = m0 + 128;  // causal: P[t, s>t] == 0 beyond this

  f32x4 acc[4][4];
#pragma unroll
  for (int i = 0; i < 4; i++)
#pragma unroll
    for (int j = 0; j < 4; j++)
#pragma unroll
      for (int k = 0; k < 4; k++) acc[i][j][k] = 0.0f;

  gemm_core(Pb + (long long)m0 * 2048, 2048, Vb + (long long)n0 * 2048, 2048, K, acc, sh, sh + 4096);

  const int tid = threadIdx.x, lane = tid & 63, w = tid >> 6;
  const int wm = (w & 1) << 6;
  const int q4 = lane >> 4;
#pragma unroll
  for (int mi = 0; mi < 4; mi++) {
    unsigned short vals[4][4];
    float inv[4];
    const int gm0 = m0 + wm + mi * 16 + q4 * 4;
#pragma unroll
    for (int rr = 0; rr < 4; rr++) inv[rr] = 1.0f / rs[gm0 + rr];
#pragma unroll
    for (int ni = 0; ni < 4; ni++)
#pragma unroll
      for (int rr = 0; rr < 4; rr++)
        vals[ni][rr] = f2bf(acc[mi][ni][rr] * inv[rr]);
    repack_store_mi(vals, sh, mi, m0, n0, 1024, O + (long long)b * 2048 * 1024);
  }
}

// ---- out = O Wf^T + bf, fp32 out (core4, 512 thr) -------------------------
__global__ __launch_bounds__(512, 2) void final_gemm(const unsigned short* __restrict__ O,
                                                     const unsigned short* __restrict__ Wf,
                                                     const float* __restrict__ bf_,
                                                     float* __restrict__ out) {
  __shared__ unsigned short lds[49152];
  float* shf = (float*)lds;
  const int tid = threadIdx.x, lane = tid & 63, w = tid >> 6;
  const int wr = w >> 2, wc = w & 3;
  const int cl = lane & 15, q4 = lane >> 4;
  const int m0 = blockIdx.x * 128;
  const int n0 = blockIdx.y * 256;

  f32x4 acc[4][4];
#pragma unroll
  for (int i = 0; i < 4; i++)
#pragma unroll
    for (int j = 0; j < 4; j++)
#pragma unroll
      for (int k = 0; k < 4; k++) acc[i][j][k] = 0.0f;

  core4(O + (long long)m0 * 1024, 1024, Wf + (long long)n0 * 1024, 1024, 32, acc, lds);

  // fp32 repack in two 64-row rounds (64 x 260 floats = 66.5 KB <= 96 KB)
#pragma unroll
  for (int r = 0; r < 2; ++r) {
    __syncthreads();
    if (wr == r) {
#pragma unroll
      for (int mi = 0; mi < 4; ++mi)
#pragma unroll
        for (int nj = 0; nj < 4; ++nj) {
          const int col = wc * 64 + nj * 16 + cl;
          const float bi = bf_[n0 + col];
#pragma unroll
          for (int rr = 0; rr < 4; ++rr)
            shf[(mi * 16 + q4 * 4 + rr) * 260 + col] = acc[mi][nj][rr] + bi;
        }
    }
    __syncthreads();
#pragma unroll
    for (int it = 0; it < 8; ++it) {
      int c = it * 512 + tid;
      int row = c >> 6, c4 = (c & 63) << 2;
      float4 v = *(const float4*)(shf + row * 260 + c4);
      *(float4*)(out + (long long)(m0 + r * 64 + row) * 1024 + n0 + c4) = v;
    }
  }
}

// ---------------------------------------------------------------------------
extern "C" void kernel_launch(void* const* d_in, const int* in_sizes, int n_in,
                              void* d_out, int out_size, void* d_ws, size_t ws_size,
                              hipStream_t stream) {
  (void)in_sizes; (void)n_in; (void)out_size; (void)ws_size;
  const float* x   = (const float*)d_in[0];
  const float* Wq  = (const float*)d_in[1];
  const float* bq  = (const float*)d_in[2];
  const float* Wk  = (const float*)d_in[3];
  const float* bk  = (const float*)d_in[4];
  const float* Wv  = (const float*)d_in[5];
  const float* bv  = (const float*)d_in[6];
  const float* Wf  = (const float*)d_in[7];
  const float* bf_ = (const float*)d_in[8];
  float* out = (float*)d_out;

  char* ws = (char*)d_ws;
  const size_t MB = 1024 * 1024;
  unsigned short* xb  = (unsigned short*)(ws);             // 16 MB
  unsigned short* Wqb = (unsigned short*)(ws + 16 * MB);   // 2 MB
  unsigned short* Wkb = (unsigned short*)(ws + 18 * MB);   // 2 MB
  unsigned short* Wvb = (unsigned short*)(ws + 20 * MB);   // 2 MB
  unsigned short* Wfb = (unsigned short*)(ws + 22 * MB);   // 2 MB
  unsigned short* Qb  = (unsigned short*)(ws + 24 * MB);   // 16 MB
  unsigned short* Kb  = (unsigned short*)(ws + 40 * MB);   // 16 MB
  unsigned short* Vtb = (unsigned short*)(ws + 56 * MB);   // 16 MB
  unsigned short* Ob  = (unsigned short*)(ws + 72 * MB);   // 16 MB
  unsigned short* Pb  = (unsigned short*)(ws + 88 * MB);   // 32 MB P bf16
  float*          rsum= (float*)(ws + 120 * MB);           // 32 KB row sums

  hipMemsetAsync(rsum, 0, 8192 * sizeof(float), stream);
  cast_all<<<dim3(3145728 / 256), dim3(256), 0, stream>>>(x, Wq, Wk, Wv, Wf, xb, Wqb, Wkb, Wvb, Wfb);
  proj_rope<<<dim3(64, 4, 3), dim3(512), 0, stream>>>(xb, Wqb, Wkb, Wvb, bq, bk, bv, Qb, Kb, Vtb);
  score_exp<<<dim3(136, 1, 4), dim3(256), 0, stream>>>(Qb, Kb, Pb, rsum);
  pv_gemm<<<dim3(16, 8, 4), dim3(256), 0, stream>>>(Pb, Vtb, rsum, Ob);
  final_gemm<<<dim3(64, 4), dim3(512), 0, stream>>>(Ob, Wfb, bf_, out);
}